// Round 7
// baseline (153.193 us; speedup 1.0000x reference)
//
#include <hip/hip_runtime.h>

#define NE 8
#define DIM 1024
#define ALPHA_C 10.0f

typedef float f32x4 __attribute__((ext_vector_type(4)));

// Full-row mapping: every x load instruction = 64 lanes x 16 B = 1 KB of ONE
// row (fully contiguous). Wave walks 16 consecutive rows (sequential 64 KB).
// 4-row register block amortizes LDS W reads; 6-step butterfly reduction.
__global__ __launch_bounds__(256, 3) void topk_gating_kernel(
    const float* __restrict__ x,
    const float* __restrict__ gw,
    const float* __restrict__ gb,
    float* __restrict__ out,
    int nrows)
{
    __shared__ f32x4 wlds[NE * DIM / 4];   // 32 KiB

    const int tid = threadIdx.x;

    // Stage W into LDS, coalesced: 2048 f32x4 / 256 thr = 8 each
    {
        const f32x4* src = (const f32x4*)gw;
        #pragma unroll
        for (int i = 0; i < 8; ++i)
            wlds[tid + i * 256] = src[tid + i * 256];
    }
    float bias[NE];
    #pragma unroll
    for (int e = 0; e < NE; ++e) bias[e] = gb[e];
    __syncthreads();

    const int lane = tid & 63;
    const int wid = (blockIdx.x * blockDim.x + tid) >> 6;
    const int rstart = wid * 16;           // 16 consecutive rows per wave
    const f32x4* x4 = (const f32x4*)x;
    const int last = nrows - 1;

    #pragma unroll 1
    for (int b = 0; b < 4; ++b) {
        const int rb = rstart + b * 4;
        if (rb >= nrows) break;
        const int r0 = rb;
        const int r1 = min(rb + 1, last);
        const int r2 = min(rb + 2, last);
        const int r3 = min(rb + 3, last);

        // ---- 16 contiguous 1-KB NT loads (c-major to match first use) ----
        f32x4 xr[4][4];
        #pragma unroll
        for (int c = 0; c < 4; ++c) {
            xr[0][c] = __builtin_nontemporal_load(&x4[(size_t)r0 * 256 + c * 64 + lane]);
            xr[1][c] = __builtin_nontemporal_load(&x4[(size_t)r1 * 256 + c * 64 + lane]);
            xr[2][c] = __builtin_nontemporal_load(&x4[(size_t)r2 * 256 + c * 64 + lane]);
            xr[3][c] = __builtin_nontemporal_load(&x4[(size_t)r3 * 256 + c * 64 + lane]);
        }

        // ---- FMA: W fragment read once, reused for 4 rows ----
        float acc[4][NE] = {};
        #pragma unroll
        for (int c = 0; c < 4; ++c) {
            #pragma unroll
            for (int e = 0; e < NE; ++e) {
                f32x4 wv = wlds[e * 256 + c * 64 + lane];
                #pragma unroll
                for (int r = 0; r < 4; ++r) {
                    acc[r][e] += xr[r][c].x * wv.x + xr[r][c].y * wv.y
                               + xr[r][c].z * wv.z + xr[r][c].w * wv.w;
                }
            }
        }

        // ---- full-wave butterfly reduce; all lanes end with all sums ----
        #pragma unroll
        for (int r = 0; r < 4; ++r) {
            #pragma unroll
            for (int e = 0; e < NE; ++e) {
                float v = acc[r][e];
                v += __shfl_xor(v, 1);
                v += __shfl_xor(v, 2);
                v += __shfl_xor(v, 4);
                v += __shfl_xor(v, 8);
                v += __shfl_xor(v, 16);
                v += __shfl_xor(v, 32);
                acc[r][e] = v + bias[e];
            }
        }

        // ---- epilogue per row (redundant on all lanes), folded into a
        //      32-lane select so the block stores one 128-B line ----
        float sel = 0.f;
        #pragma unroll
        for (int r = 0; r < 4; ++r) {
            float m1 = -INFINITY, m2 = -INFINITY;
            #pragma unroll
            for (int e = 0; e < NE; ++e) {
                float v = acc[r][e];
                float nm2 = fmaxf(m2, fminf(m1, v));
                m1 = fmaxf(m1, v);
                m2 = nm2;
            }

            float ex[NE];
            float sum = 0.f;
            #pragma unroll
            for (int e = 0; e < NE; ++e) {
                ex[e] = __expf(acc[r][e] - m1);
                sum += ex[e];
            }
            float inv = 1.f / sum;

            float o[NE];
            #pragma unroll
            for (int e = 0; e < NE; ++e) {
                float s = ex[e] * inv;
                float topv = ALPHA_C * (__expf(s) - 1.f);
                float lowv = ALPHA_C * __logf(1.f + s);
                o[e] = (acc[r][e] >= m2) ? topv : lowv;
            }

            float om = o[0];
            #pragma unroll
            for (int e = 1; e < NE; ++e) om = fmaxf(om, o[e]);
            float oex[NE];
            float osum = 0.f;
            #pragma unroll
            for (int e = 0; e < NE; ++e) {
                oex[e] = __expf(o[e] - om);
                osum += oex[e];
            }
            float oinv = 1.f / osum;

            #pragma unroll
            for (int e = 0; e < NE; ++e) {
                float gv = oex[e] * oinv;
                sel = (lane == r * 8 + e) ? gv : sel;
            }
        }

        // lanes 0..31 store gates for rows rb..rb+3: one contiguous 128 B
        if (lane < 32 && (rb + (lane >> 3)) < nrows)
            out[(size_t)rb * 8 + lane] = sel;
    }
}

extern "C" void kernel_launch(void* const* d_in, const int* in_sizes, int n_in,
                              void* d_out, int out_size, void* d_ws, size_t ws_size,
                              hipStream_t stream) {
    const float* x  = (const float*)d_in[0];
    const float* gw = (const float*)d_in[1];
    const float* gb = (const float*)d_in[2];
    float* out = (float*)d_out;
    const int nrows = in_sizes[0] / DIM;

    const int block = 256;   // 4 waves/block, 32 KiB LDS
    const int grid = 2048;   // 8192 waves x 16 rows = 131072 rows, exact cover
    topk_gating_kernel<<<grid, block, 0, stream>>>(x, gw, gb, out, nrows);
}

// Round 8
// 119.681 us; speedup vs baseline: 1.2800x; 1.2800x over previous
//
#include <hip/hip_runtime.h>

#define NE 8
#define DIM 1024
#define ALPHA_C 10.0f

typedef float f32x4 __attribute__((ext_vector_type(4)));

// 8 lanes per row, 8 rows per wave. Every x wave-load segment = one full
// 128-B cache line, NT (no cache allocation). W in LDS, broadcast reads.
// Launch shape: 512-thr blocks, grid = 4 blocks/CU exactly resident ->
// 32 waves/CU, zero dispatch tail (each wave does exactly 2 iterations).
__global__ __launch_bounds__(512, 8) void topk_gating_kernel(
    const float* __restrict__ x,
    const float* __restrict__ gw,
    const float* __restrict__ gb,
    float* __restrict__ out,
    int nrows)
{
    __shared__ float wlds[NE * DIM];   // 32 KiB

    const int tid = threadIdx.x;

    // Stage W into LDS, coalesced: 2048 float4 / 512 thr = 4 each
    {
        const float4* src = (const float4*)gw;
        float4* dst = (float4*)wlds;
        #pragma unroll
        for (int i = 0; i < 4; ++i)
            dst[tid + i * 512] = src[tid + i * 512];
    }
    float bias[NE];
    #pragma unroll
    for (int e = 0; e < NE; ++e) bias[e] = gb[e];
    __syncthreads();

    const int lane = tid & 63;
    const int g = lane >> 3;          // row-within-group-of-8
    const int s = lane & 7;           // sub-lane within row (128-B line index)
    const int wid = (blockIdx.x * blockDim.x + tid) >> 6;
    const int nwaves = (gridDim.x * blockDim.x) >> 6;

    const f32x4* x4 = (const f32x4*)x;
    const f32x4* w4 = (const f32x4*)wlds;

    for (int base = wid * 8; base < nrows; base += nwaves * 8) {
        const int row = base + g;
        const bool valid = row < nrows;
        const size_t xoff = (size_t)row * (DIM / 4) + s;

        float acc[NE] = {0.f, 0.f, 0.f, 0.f, 0.f, 0.f, 0.f, 0.f};
        if (valid) {
            // 32 j-steps; each wave-instruction reads 8 rows x 128 B = 8 full lines
            #pragma unroll 4
            for (int j = 0; j < 32; ++j) {
                f32x4 xv = __builtin_nontemporal_load(&x4[xoff + (size_t)j * 8]);
                #pragma unroll
                for (int e = 0; e < NE; ++e) {
                    // 8 unique LDS addresses per wave instr -> broadcast, cheap
                    f32x4 wv = w4[e * (DIM / 4) + j * 8 + s];
                    acc[e] += xv.x * wv.x + xv.y * wv.y + xv.z * wv.z + xv.w * wv.w;
                }
            }
        }

        // Allgather butterfly over the 8 lanes of each row: one shuffle
        // instruction reduces all 8 rows of the wave in parallel.
        #pragma unroll
        for (int e = 0; e < NE; ++e) {
            float v = acc[e];
            v += __shfl_xor(v, 1);
            v += __shfl_xor(v, 2);
            v += __shfl_xor(v, 4);
            acc[e] = v + bias[e];
        }

        // ---- epilogue (redundant across the 8 lanes of a row) ----
        // max and 2nd-largest (duplicate-preserving == kthvalue semantics)
        float m1 = -INFINITY, m2 = -INFINITY;
        #pragma unroll
        for (int e = 0; e < NE; ++e) {
            float v = acc[e];
            float nm2 = fmaxf(m2, fminf(m1, v));
            m1 = fmaxf(m1, v);
            m2 = nm2;
        }

        // softmax of raw logits
        float ex[NE];
        float sum = 0.f;
        #pragma unroll
        for (int e = 0; e < NE; ++e) {
            ex[e] = __expf(acc[e] - m1);
            sum += ex[e];
        }
        float inv = 1.f / sum;

        // decomposition: (l < kth) -> ALPHA*log1p(s), else ALPHA*(exp(s)-1)
        float o[NE];
        #pragma unroll
        for (int e = 0; e < NE; ++e) {
            float sft = ex[e] * inv;
            float topv = ALPHA_C * (__expf(sft) - 1.f);
            float lowv = ALPHA_C * __logf(1.f + sft);
            o[e] = (acc[e] >= m2) ? topv : lowv;
        }

        // final softmax
        float om = o[0];
        #pragma unroll
        for (int e = 1; e < NE; ++e) om = fmaxf(om, o[e]);
        float oex[NE];
        float osum = 0.f;
        #pragma unroll
        for (int e = 0; e < NE; ++e) {
            oex[e] = __expf(o[e] - om);
            osum += oex[e];
        }
        float oinv = 1.f / osum;

        // lane s writes gates[s]; compile-time-index select chain (no scratch)
        float gsel = oex[0] * oinv;
        #pragma unroll
        for (int e = 1; e < NE; ++e) {
            float ge = oex[e] * oinv;
            gsel = (s == e) ? ge : gsel;
        }
        if (valid) __builtin_nontemporal_store(gsel, &out[(size_t)row * NE + s]);
    }
}

extern "C" void kernel_launch(void* const* d_in, const int* in_sizes, int n_in,
                              void* d_out, int out_size, void* d_ws, size_t ws_size,
                              hipStream_t stream) {
    const float* x  = (const float*)d_in[0];
    const float* gw = (const float*)d_in[1];
    const float* gb = (const float*)d_in[2];
    float* out = (float*)d_out;
    const int nrows = in_sizes[0] / DIM;

    const int block = 512;   // 8 waves/block, 32 KiB LDS; 4 blocks/CU resident
    const int grid = 1024;   // exactly 4/CU -> 32 waves/CU, zero dispatch tail
    topk_gating_kernel<<<grid, block, 0, stream>>>(x, gw, gb, out, nrows);
}